// Round 10
// baseline (156.393 us; speedup 1.0000x reference)
//
#include <hip/hip_runtime.h>
#include <hip/hip_cooperative_groups.h>

namespace cg = cooperative_groups;

#define NTOK 4096
#define DMODEL 512
#define NHEAD 8
#define HDIM 64
#define KDIM 512
#define KITER (KDIM / 64)
#define NBLK 256

typedef __bf16 bf16x8 __attribute__((ext_vector_type(8)));
typedef float f32x4 __attribute__((ext_vector_type(4)));
typedef unsigned short u16x8 __attribute__((ext_vector_type(8)));
typedef unsigned short u16x4 __attribute__((ext_vector_type(4)));

#define NEGINF (-__builtin_inff())

__device__ __forceinline__ f32x4 mfma16(bf16x8 a, bf16x8 b, f32x4 c) {
  return __builtin_amdgcn_mfma_f32_16x16x32_bf16(a, b, c, 0, 0, 0);
}

__device__ __forceinline__ unsigned short f2bf(float f) {
  unsigned u = __builtin_bit_cast(unsigned, f);
  u += 0x7FFFu + ((u >> 16) & 1u);
  return (unsigned short)(u >> 16);
}

__device__ __forceinline__ void gload_lds16(const void* g, void* l) {
  __builtin_amdgcn_global_load_lds(
      (const __attribute__((address_space(1))) void*)g,
      (__attribute__((address_space(3))) void*)l, 16, 0, 0);
}

// ---------------- phase 0: convert fp32->bf16 (+qrange table) -------------
__device__ __forceinline__ void convert_phase(
    const float* __restrict__ x,
    const float* __restrict__ Wq, const float* __restrict__ bq,
    const float* __restrict__ Wk, const float* __restrict__ bk,
    const float* __restrict__ Wv, const float* __restrict__ bv,
    const float* __restrict__ Wo, const int* __restrict__ batch,
    unsigned short* __restrict__ xb, unsigned short* __restrict__ wqkv,
    unsigned short* __restrict__ wo, float* __restrict__ bqkv,
    int* __restrict__ qrange, int* bsh) {
  if (blockIdx.x == 0) {
    for (int i = threadIdx.x; i < NTOK; i += blockDim.x) bsh[i] = batch[i];
  }
  const int XV = NTOK * DMODEL / 4;   // 524288
  const int WV = DMODEL * DMODEL / 4; // 65536
  const int total = XV + 4 * WV + 1536 / 4;
  const int stride = gridDim.x * blockDim.x;
  for (int i = blockIdx.x * blockDim.x + threadIdx.x; i < total; i += stride) {
    if (i < XV) {
      float4 v = ((const float4*)x)[i];
      u16x4 pk = {f2bf(v.x), f2bf(v.y), f2bf(v.z), f2bf(v.w)};
      *(u16x4*)(xb + (size_t)i * 4) = pk;
    } else if (i < XV + 3 * WV) {
      int j = i - XV;
      const float* W; float sc; int jj;
      if (j < WV)          { W = Wq; sc = 0.125f; jj = j; }
      else if (j < 2 * WV) { W = Wk; sc = 1.0f;  jj = j - WV; }
      else                 { W = Wv; sc = 1.0f;  jj = j - 2 * WV; }
      float4 v = ((const float4*)W)[jj];
      u16x4 pk = {f2bf(v.x * sc), f2bf(v.y * sc), f2bf(v.z * sc), f2bf(v.w * sc)};
      *(u16x4*)(wqkv + (size_t)j * 4) = pk;
    } else if (i < XV + 4 * WV) {
      int j = i - XV - 3 * WV;
      float4 v = ((const float4*)Wo)[j];
      u16x4 pk = {f2bf(v.x), f2bf(v.y), f2bf(v.z), f2bf(v.w)};
      *(u16x4*)(wo + (size_t)j * 4) = pk;
    } else {
      int j = (i - XV - 4 * WV) * 4;
      #pragma unroll
      for (int t = 0; t < 4; ++t) {
        int e = j + t;
        float v = (e < 512) ? bq[e] * 0.125f
                 : (e < 1024 ? bk[e - 512] : bv[e - 1024]);
        bqkv[e] = v;
      }
    }
  }
  if (blockIdx.x == 0) {
    __syncthreads();
    if (threadIdx.x < 256) {
      int q0 = threadIdx.x * 16;
      int blo = bsh[q0];
      int bhi = bsh[q0 + 15];
      int lo = 0, hi = NTOK;
      while (lo < hi) { int m = (lo + hi) >> 1; if (bsh[m] < blo) lo = m + 1; else hi = m; }
      qrange[threadIdx.x * 2] = lo >> 6;
      lo = 0; hi = NTOK;
      while (lo < hi) { int m = (lo + hi) >> 1; if (bsh[m] < bhi + 1) lo = m + 1; else hi = m; }
      qrange[threadIdx.x * 2 + 1] = (lo + 63) >> 6;
    }
    __syncthreads();
  }
}

// ---------------- GEMM tile: C = A(bf16) @ B^T(bf16) + bias ---------------
// Round-5 body. 2-buffer 1-ahead counted-vmcnt pipeline. Leading vmcnt(0)
// drains dangling VMEM from prior phases/tiles (hand vmcnt is blind to them).
template <int MODE>
__device__ __forceinline__ void gemm_tile(
    const unsigned short* __restrict__ A,
    const unsigned short* __restrict__ B,
    const float* __restrict__ biasv,
    float* __restrict__ outf,
    unsigned short* __restrict__ qb,
    unsigned short* __restrict__ kb,
    unsigned short* __restrict__ vt,
    int mt, int nt, unsigned short* lds) {
  constexpr int BM = MODE ? 64 : 128;
  constexpr int FM = MODE ? 2 : 4;
  constexpr int ALOADS = BM / 32;
  constexpr int BUFBYTES = (BM + 64) * 64 * 2;
  const int tid = threadIdx.x;
  const int lane = tid & 63;
  const int wv = tid >> 6;
  const int wm = wv >> 1, wn = wv & 1;
  const int r16 = lane & 15, g4 = lane >> 4;

  f32x4 acc[FM][2];
  #pragma unroll
  for (int i = 0; i < FM; ++i)
    #pragma unroll
    for (int j = 0; j < 2; ++j)
      acc[i][j] = (f32x4){0.f, 0.f, 0.f, 0.f};

  const int srow = tid >> 3;
  const int scolb = (tid & 7) << 4;

#define STAGE(KT, BI)                                                        \
  {                                                                          \
    char* bA = (char*)lds + (BI) * BUFBYTES;                                 \
    char* bB = bA + BM * 128;                                                \
    _Pragma("unroll") for (int i = 0; i < ALOADS; ++i) {                     \
      int row = i * 32 + srow;                                               \
      int cu_ = scolb ^ ((row & 7) << 4);                                    \
      gload_lds16(A + (size_t)(mt * BM + row) * KDIM + (KT) * 64 + (cu_ >> 1), \
                  bA + i * 4096 + wv * 1024);                                \
    }                                                                        \
    _Pragma("unroll") for (int i = 0; i < 2; ++i) {                          \
      int row = i * 32 + srow;                                               \
      int cu_ = scolb ^ ((row & 7) << 4);                                    \
      gload_lds16(B + (size_t)(nt * 64 + row) * KDIM + (KT) * 64 + (cu_ >> 1), \
                  bB + i * 4096 + wv * 1024);                                \
    }                                                                        \
  }

#define COMPUTE(BI)                                                          \
  {                                                                          \
    const char* base = (const char*)lds + (BI) * BUFBYTES;                   \
    _Pragma("unroll") for (int ks = 0; ks < 2; ++ks) {                       \
      bf16x8 af[FM], bfr[2];                                                 \
      _Pragma("unroll") for (int f = 0; f < FM; ++f) {                       \
        int ra = wm * (FM * 16) + f * 16 + r16;                              \
        af[f] = *(const bf16x8*)(base + ra * 128 +                           \
                                 ((ks * 64 + g4 * 16) ^ ((ra & 7) << 4)));   \
      }                                                                      \
      _Pragma("unroll") for (int f = 0; f < 2; ++f) {                        \
        int rb = wn * 32 + f * 16 + r16;                                     \
        bfr[f] = *(const bf16x8*)(base + BM * 128 + rb * 128 +               \
                                  ((ks * 64 + g4 * 16) ^ ((rb & 7) << 4)));  \
      }                                                                      \
      _Pragma("unroll") for (int fm = 0; fm < FM; ++fm)                      \
        _Pragma("unroll") for (int fn = 0; fn < 2; ++fn)                     \
          acc[fm][fn] = mfma16(af[fm], bfr[fn], acc[fm][fn]);                \
    }                                                                        \
  }

  asm volatile("s_waitcnt vmcnt(0)" ::: "memory");  // drain prior phase/tile
  __syncthreads();                                  // LDS reuse safe
  STAGE(0, 0);
  #pragma unroll
  for (int kt = 0; kt < KITER; ++kt) {
    if (kt + 1 < KITER) {
      __builtin_amdgcn_s_barrier();   // WAR: compute(kt-1) done before overwrite
      STAGE(kt + 1, (kt + 1) & 1);
      if constexpr (MODE == 0)
        asm volatile("s_waitcnt vmcnt(6)" ::: "memory");
      else
        asm volatile("s_waitcnt vmcnt(4)" ::: "memory");
    } else {
      asm volatile("s_waitcnt vmcnt(0)" ::: "memory");
    }
    __builtin_amdgcn_s_barrier();     // RAW: all waves' stage(kt) visible
    COMPUTE(kt & 1);
  }
#undef STAGE
#undef COMPUTE

  #pragma unroll
  for (int fm = 0; fm < FM; ++fm) {
    #pragma unroll
    for (int fn = 0; fn < 2; ++fn) {
      int mb = mt * BM + wm * (FM * 16) + fm * 16 + g4 * 4;
      int n = nt * 64 + wn * 32 + fn * 16 + r16;
      float bv = biasv[n];
      if (MODE == 1) {
        #pragma unroll
        for (int r = 0; r < 4; ++r)
          outf[(size_t)(mb + r) * DMODEL + n] = acc[fm][fn][r] + bv;
      } else {
        if (n < 512) {
          #pragma unroll
          for (int r = 0; r < 4; ++r)
            qb[(size_t)(mb + r) * DMODEL + n] = f2bf(acc[fm][fn][r] + bv);
        } else if (n < 1024) {
          int nn = n - 512;
          #pragma unroll
          for (int r = 0; r < 4; ++r)
            kb[(size_t)(mb + r) * DMODEL + nn] = f2bf(acc[fm][fn][r] + bv);
        } else {
          int nn = n - 1024;  // nn = h*64 + d ; vt[nn][m]
          u16x4 pk;
          #pragma unroll
          for (int r = 0; r < 4; ++r) pk[r] = f2bf(acc[fm][fn][r] + bv);
          *(u16x4*)(vt + (size_t)nn * NTOK + mb) = pk;
        }
      }
    }
  }
}

// ---------------- phase 2: flash attention (round-5 body, per-wave) -------
__device__ __forceinline__ void attn_task(
    const unsigned short* __restrict__ qb,
    const unsigned short* __restrict__ kb,
    const unsigned short* __restrict__ vt,
    const float* __restrict__ bias,
    const int* __restrict__ batch,
    const int* __restrict__ qrange,
    unsigned short* __restrict__ ao,
    int h, int qt, unsigned short* pl) {
  const int lane = threadIdx.x & 63;
  const int r16 = lane & 15, g4 = lane >> 4;
  const int qrow0 = qt * 16;
  const int hoff = h * HDIM;

  const unsigned short* qrow = qb + (size_t)(qrow0 + r16) * DMODEL + hoff + g4 * 8;
  bf16x8 qa0 = *(const bf16x8*)qrow;
  bf16x8 qa1 = *(const bf16x8*)(qrow + 32);

  int qbt[4];
  const float* bprow[4];
  const float* bh = bias + (size_t)h * NTOK * NTOK;
  #pragma unroll
  for (int r = 0; r < 4; ++r) {
    qbt[r] = batch[qrow0 + g4 * 4 + r];
    bprow[r] = bh + (size_t)(qrow0 + g4 * 4 + r) * NTOK;
  }

  const int tile0 = qrange[qt * 2];
  const int tile1 = qrange[qt * 2 + 1];

  float m_r[4] = {NEGINF, NEGINF, NEGINF, NEGINF};
  float l_r[4] = {0.f, 0.f, 0.f, 0.f};
  f32x4 o[4];
  #pragma unroll
  for (int d = 0; d < 4; ++d) o[d] = (f32x4){0.f, 0.f, 0.f, 0.f};

#define PREFETCH_KB(T, K0, K1, BV, KBT)                                      \
  {                                                                          \
    int kvb_ = (T) << 6;                                                     \
    _Pragma("unroll") for (int c = 0; c < 4; ++c) {                          \
      const unsigned short* kp =                                             \
          kb + (size_t)(kvb_ + c * 16 + r16) * DMODEL + hoff + g4 * 8;       \
      K0[c] = *(const bf16x8*)kp;                                            \
      K1[c] = *(const bf16x8*)(kp + 32);                                     \
    }                                                                        \
    _Pragma("unroll") for (int c = 0; c < 4; ++c) {                          \
      KBT[c] = batch[kvb_ + c * 16 + r16];                                   \
      _Pragma("unroll") for (int r = 0; r < 4; ++r)                          \
        BV[c][r] = bprow[r][kvb_ + c * 16 + r16];                            \
    }                                                                        \
  }

#define TILE_STEP(T, K0C, K1C, BVC, KBTC, K0N, K1N, BVN, KBTN)               \
  {                                                                          \
    int kvb = (T) << 6;                                                      \
    f32x4 s[4];                                                              \
    __builtin_amdgcn_s_setprio(1);                                           \
    _Pragma("unroll") for (int c = 0; c < 4; ++c) {                          \
      f32x4 z = (f32x4){0.f, 0.f, 0.f, 0.f};                                 \
      z = mfma16(qa0, K0C[c], z);                                            \
      z = mfma16(qa1, K1C[c], z);                                            \
      s[c] = z;                                                              \
    }                                                                        \
    __builtin_amdgcn_s_setprio(0);                                           \
    bf16x8 v0[4], v1[4];                                                     \
    _Pragma("unroll") for (int d = 0; d < 4; ++d) {                          \
      const unsigned short* vp =                                             \
          vt + (size_t)(hoff + d * 16 + r16) * NTOK + kvb + g4 * 8;          \
      v0[d] = *(const bf16x8*)vp;                                            \
      v1[d] = *(const bf16x8*)(vp + 32);                                     \
    }                                                                        \
    {                                                                        \
      int tn_ = ((T) + 1 < tile1) ? (T) + 1 : (T);                           \
      PREFETCH_KB(tn_, K0N, K1N, BVN, KBTN);                                 \
    }                                                                        \
    _Pragma("unroll") for (int c = 0; c < 4; ++c)                            \
      _Pragma("unroll") for (int r = 0; r < 4; ++r)                          \
        s[c][r] = (qbt[r] == KBTC[c]) ? (s[c][r] + BVC[c][r]) : NEGINF;      \
    float scl[4];                                                            \
    _Pragma("unroll") for (int r = 0; r < 4; ++r) {                          \
      float tm = fmaxf(fmaxf(s[0][r], s[1][r]), fmaxf(s[2][r], s[3][r]));    \
      tm = fmaxf(tm, __shfl_xor(tm, 1));                                     \
      tm = fmaxf(tm, __shfl_xor(tm, 2));                                     \
      tm = fmaxf(tm, __shfl_xor(tm, 4));                                     \
      tm = fmaxf(tm, __shfl_xor(tm, 8));                                     \
      float mn = fmaxf(m_r[r], tm);                                          \
      bool dead = (mn == NEGINF);                                            \
      scl[r] = dead ? 1.0f : __expf(m_r[r] - mn);                            \
      m_r[r] = mn;                                                           \
      float rs = 0.f;                                                        \
      _Pragma("unroll") for (int c = 0; c < 4; ++c) {                        \
        float p = dead ? 0.0f : __expf(s[c][r] - mn);                        \
        s[c][r] = p;                                                         \
        rs += p;                                                             \
      }                                                                      \
      rs += __shfl_xor(rs, 1);                                               \
      rs += __shfl_xor(rs, 2);                                               \
      rs += __shfl_xor(rs, 4);                                               \
      rs += __shfl_xor(rs, 8);                                               \
      l_r[r] = l_r[r] * scl[r] + rs;                                         \
    }                                                                        \
    _Pragma("unroll") for (int c = 0; c < 4; ++c)                            \
      _Pragma("unroll") for (int r = 0; r < 4; ++r)                          \
        pl[(g4 * 4 + r) * 72 + c * 16 + r16] = f2bf(s[c][r]);                \
    asm volatile("" ::: "memory");                                           \
    u16x8 pr0 = *(const u16x8*)(pl + r16 * 72 + g4 * 8);                     \
    u16x8 pr1 = *(const u16x8*)(pl + r16 * 72 + 32 + g4 * 8);                \
    bf16x8 pa0 = __builtin_bit_cast(bf16x8, pr0);                            \
    bf16x8 pa1 = __builtin_bit_cast(bf16x8, pr1);                            \
    _Pragma("unroll") for (int d = 0; d < 4; ++d) {                          \
      _Pragma("unroll") for (int r = 0; r < 4; ++r) o[d][r] *= scl[r];       \
    }                                                                        \
    __builtin_amdgcn_s_setprio(1);                                           \
    _Pragma("unroll") for (int d = 0; d < 4; ++d) {                          \
      o[d] = mfma16(pa0, v0[d], o[d]);                                       \
      o[d] = mfma16(pa1, v1[d], o[d]);                                       \
    }                                                                        \
    __builtin_amdgcn_s_setprio(0);                                           \
  }

  bf16x8 ka0[4], ka1[4], kc0[4], kc1[4];
  float bva[4][4], bvb[4][4];
  int kta[4], ktb[4];
  PREFETCH_KB(tile0, ka0, ka1, bva, kta);
  int t = tile0;
  while (true) {
    TILE_STEP(t, ka0, ka1, bva, kta, kc0, kc1, bvb, ktb);
    if (++t >= tile1) break;
    TILE_STEP(t, kc0, kc1, bvb, ktb, ka0, ka1, bva, kta);
    if (++t >= tile1) break;
  }

  #pragma unroll
  for (int r = 0; r < 4; ++r) {
    float inv = (l_r[r] > 0.f) ? 1.0f / l_r[r] : 0.0f;
    #pragma unroll
    for (int d = 0; d < 4; ++d)
      ao[(size_t)(qrow0 + g4 * 4 + r) * DMODEL + hoff + d * 16 + r16] =
          f2bf(o[d][r] * inv);
  }
#undef PREFETCH_KB
#undef TILE_STEP
}

// ---------------- fused persistent kernel (cooperative, 256 blocks) -------
struct FusedArgs {
  const float* x; const float* ab; const int* batch;
  const float* Wq; const float* bq; const float* Wk; const float* bk;
  const float* Wv; const float* bv; const float* Wo; const float* bo;
  float* out;
  unsigned short* xb; unsigned short* qb; unsigned short* kb;
  unsigned short* vt; unsigned short* aout; unsigned short* wqkv;
  unsigned short* wo; float* bqkv; int* qrange;
};

__global__ __launch_bounds__(256, 2) void fused_kernel(FusedArgs a) {
  __shared__ __align__(16) unsigned char uLDS[49152];  // 48KB union
  cg::grid_group grid = cg::this_grid();

  // phase 0: convert + qrange
  convert_phase(a.x, a.Wq, a.bq, a.Wk, a.bk, a.Wv, a.bv, a.Wo, a.batch,
                a.xb, a.wqkv, a.wo, a.bqkv, a.qrange, (int*)uLDS);
  grid.sync();

  // phase 1: QKV projection GEMM, 768 tiles (mt 32 x nt 24), 3 per block
  for (int t = blockIdx.x; t < 768; t += NBLK)
    gemm_tile<0>(a.xb, a.wqkv, a.bqkv, nullptr, a.qb, a.kb, a.vt,
                 t & 31, t >> 5, (unsigned short*)uLDS);
  grid.sync();

  // phase 2: flash attention, 2048 wave-tasks over 1024 waves (2 each)
  {
    unsigned short* pl = (unsigned short*)uLDS + (threadIdx.x >> 6) * (16 * 72);
    int wid = blockIdx.x * 4 + (threadIdx.x >> 6);
    for (int task = wid; task < 2048; task += NBLK * 4)
      attn_task(a.qb, a.kb, a.vt, a.ab, a.batch, a.qrange, a.aout,
                task & 7, task >> 3, pl);
  }
  grid.sync();

  // phase 3: output projection GEMM, 512 tiles (mt 64 x nt 8), 2 per block
  for (int t = blockIdx.x; t < 512; t += NBLK)
    gemm_tile<1>(a.aout, a.wo, a.bo, a.out, nullptr, nullptr, nullptr,
                 t & 63, t >> 6, (unsigned short*)uLDS);
}

// ---------------- fallback: round-5 split (same bodies, thin wrappers) ----
__global__ void convert_kernel_w(FusedArgs a) {
  __shared__ int bsh[NTOK];
  convert_phase(a.x, a.Wq, a.bq, a.Wk, a.bk, a.Wv, a.bv, a.Wo, a.batch,
                a.xb, a.wqkv, a.wo, a.bqkv, a.qrange, bsh);
}

template <int MODE>
__global__ __launch_bounds__(256, MODE ? 2 : 3) void gemm_kernel_w(FusedArgs a) {
  constexpr int BM = MODE ? 64 : 128;
  __shared__ __align__(16) unsigned short lds[(BM + 64) * 64 * 2];
  if (MODE == 0)
    gemm_tile<0>(a.xb, a.wqkv, a.bqkv, nullptr, a.qb, a.kb, a.vt,
                 blockIdx.x, blockIdx.y, lds);
  else
    gemm_tile<1>(a.aout, a.wo, a.bo, a.out, nullptr, nullptr, nullptr,
                 blockIdx.x, blockIdx.y, lds);
}

__global__ __launch_bounds__(64) void attn_kernel_w(FusedArgs a) {
  __shared__ __align__(16) unsigned short pl[16 * 72];
  attn_task(a.qb, a.kb, a.vt, a.ab, a.batch, a.qrange, a.aout,
            blockIdx.x & 7, blockIdx.x >> 3, pl);
}

// ---------------------------------------------------------------------------
extern "C" void kernel_launch(void* const* d_in, const int* in_sizes, int n_in,
                              void* d_out, int out_size, void* d_ws, size_t ws_size,
                              hipStream_t stream) {
  char* ws = (char*)d_ws;
  const size_t MB = 1024 * 1024;

  FusedArgs a;
  a.x  = (const float*)d_in[0];
  a.ab = (const float*)d_in[1];
  a.batch = (const int*)d_in[2];
  a.Wq = (const float*)d_in[3];
  a.bq = (const float*)d_in[4];
  a.Wk = (const float*)d_in[5];
  a.bk = (const float*)d_in[6];
  a.Wv = (const float*)d_in[7];
  a.bv = (const float*)d_in[8];
  a.Wo = (const float*)d_in[9];
  a.bo = (const float*)d_in[10];
  a.out = (float*)d_out;
  a.xb   = (unsigned short*)(ws);            // 4 MB
  a.qb   = (unsigned short*)(ws + 4 * MB);   // 4 MB
  a.kb   = (unsigned short*)(ws + 8 * MB);   // 4 MB
  a.vt   = (unsigned short*)(ws + 12 * MB);  // 4 MB  [h*64+d][n]
  a.aout = (unsigned short*)(ws + 16 * MB);  // 4 MB
  a.wqkv = (unsigned short*)(ws + 20 * MB);  // 1.5 MB
  a.wo   = (unsigned short*)(ws + 22 * MB);  // 0.5 MB
  a.bqkv   = (float*)(ws + 23 * MB);         // 6 KB
  a.qrange = (int*)(ws + 23 * MB + 65536);   // 2 KB

  void* kp[] = {&a};
  hipError_t err = hipLaunchCooperativeKernel(
      (void*)fused_kernel, dim3(NBLK), dim3(256), kp, 0, stream);

  if (err != hipSuccess) {
    // deterministic fallback: the round-5 4-kernel split (same device bodies)
    convert_kernel_w<<<dim3(1024), dim3(256), 0, stream>>>(a);
    gemm_kernel_w<0><<<dim3(32, 24), dim3(256), 0, stream>>>(a);
    attn_kernel_w<<<dim3(2048), dim3(64), 0, stream>>>(a);
    gemm_kernel_w<1><<<dim3(64, 8), dim3(256), 0, stream>>>(a);
  }
}

// Round 11
// 52.298 us; speedup vs baseline: 2.9904x; 2.9904x over previous
//
#include <hip/hip_runtime.h>

#define NTOK 4096
#define DMODEL 512
#define NHEAD 8
#define HDIM 64
#define KDIM 512
#define KITER (KDIM / 64)

typedef __bf16 bf16x8 __attribute__((ext_vector_type(8)));
typedef float f32x4 __attribute__((ext_vector_type(4)));
typedef unsigned short u16x8 __attribute__((ext_vector_type(8)));
typedef unsigned short u16x4 __attribute__((ext_vector_type(4)));

#define NEGINF (-__builtin_inff())

__device__ __forceinline__ f32x4 mfma16(bf16x8 a, bf16x8 b, f32x4 c) {
  return __builtin_amdgcn_mfma_f32_16x16x32_bf16(a, b, c, 0, 0, 0);
}

__device__ __forceinline__ unsigned short f2bf(float f) {
  unsigned u = __builtin_bit_cast(unsigned, f);
  u += 0x7FFFu + ((u >> 16) & 1u);
  return (unsigned short)(u >> 16);
}

__device__ __forceinline__ int lbound(const int* __restrict__ b, int val) {
  int lo = 0, hi = NTOK;
  while (lo < hi) {
    int mid = (lo + hi) >> 1;
    if (b[mid] < val) lo = mid + 1; else hi = mid;
  }
  return lo;
}

// ======================= GEMM 0: fused convert + QKV =======================
// C[4096x1536] = x(fp32)@{Wq*0.125,Wk,Wv}^T + {bq*0.125,bk,bv} -> qb/kb/vt^T
// BM=128,BN=64,BK=64. Reg-staged fp32 loads -> cvt bf16 -> swizzled ds_write
// (same LDS layout as the r5 gload_lds version; COMPUTE unchanged).
// Raw-barrier T14 pipeline: loads for kt+1 stay in flight across barriers.
// Block (0,0) additionally computes the attn qrange table at its tail.
#define BUFB0 (192 * 64 * 2)  // bytes per LDS buffer (A 128x64 + B 64x64 bf16)

__global__ __launch_bounds__(256, 2) void gemm_qkv(
    const float* __restrict__ x,
    const float* __restrict__ Wq, const float* __restrict__ bq,
    const float* __restrict__ Wk, const float* __restrict__ bk,
    const float* __restrict__ Wv, const float* __restrict__ bvv,
    const int* __restrict__ batch,
    unsigned short* __restrict__ qb,
    unsigned short* __restrict__ kb,
    unsigned short* __restrict__ vt,
    int* __restrict__ qrange) {
  __shared__ __align__(16) unsigned short lds[2 * 192 * 64];
  const int tid = threadIdx.x;
  const int lane = tid & 63;
  const int wv = tid >> 6;
  const int wm = wv >> 1, wn = wv & 1;
  const int r16 = lane & 15, g4 = lane >> 4;
  const int mt = blockIdx.x, nt = blockIdx.y;

  // B source: which W + scale (uniform per block; nt<8:Q, <16:K, else V)
  const float* WB = (nt < 8) ? Wq : (nt < 16 ? Wk : Wv);
  const float wscale = (nt < 8) ? 0.125f : 1.0f;
  const int wrow0 = (nt & 7) * 64;

  f32x4 acc[4][2];
  #pragma unroll
  for (int i = 0; i < 4; ++i)
    #pragma unroll
    for (int j = 0; j < 2; ++j)
      acc[i][j] = (f32x4){0.f, 0.f, 0.f, 0.f};

  const int srow = tid >> 3;      // 0..31
  const int c0 = (tid & 7) * 8;   // bf16 col within 64

#define LOADR0(KT, RA, RB)                                                   \
  {                                                                          \
    _Pragma("unroll") for (int i = 0; i < 4; ++i) {                          \
      int row = i * 32 + srow;                                               \
      int cs = c0 ^ ((row & 7) * 8);                                         \
      const float* src = x + (size_t)(mt * 128 + row) * KDIM + (KT) * 64 + cs;\
      RA[2 * i]     = *(const f32x4*)src;                                    \
      RA[2 * i + 1] = *(const f32x4*)(src + 4);                              \
    }                                                                        \
    _Pragma("unroll") for (int i = 0; i < 2; ++i) {                          \
      int row = i * 32 + srow;                                               \
      int cs = c0 ^ ((row & 7) * 8);                                         \
      const float* src = WB + (size_t)(wrow0 + row) * KDIM + (KT) * 64 + cs; \
      RB[2 * i]     = *(const f32x4*)src;                                    \
      RB[2 * i + 1] = *(const f32x4*)(src + 4);                              \
    }                                                                        \
  }

#define WRITER0(BI, RA, RB)                                                  \
  {                                                                          \
    char* bA = (char*)lds + (BI) * BUFB0;                                    \
    char* bB = bA + 128 * 128;                                               \
    _Pragma("unroll") for (int i = 0; i < 4; ++i) {                          \
      u16x8 pk;                                                              \
      _Pragma("unroll") for (int e = 0; e < 4; ++e) {                        \
        pk[e]     = f2bf(RA[2 * i][e]);                                      \
        pk[e + 4] = f2bf(RA[2 * i + 1][e]);                                  \
      }                                                                      \
      *(u16x8*)(bA + i * 4096 + tid * 16) = pk;                              \
    }                                                                        \
    _Pragma("unroll") for (int i = 0; i < 2; ++i) {                          \
      u16x8 pk;                                                              \
      _Pragma("unroll") for (int e = 0; e < 4; ++e) {                        \
        pk[e]     = f2bf(RB[2 * i][e] * wscale);                             \
        pk[e + 4] = f2bf(RB[2 * i + 1][e] * wscale);                         \
      }                                                                      \
      *(u16x8*)(bB + i * 4096 + tid * 16) = pk;                              \
    }                                                                        \
  }

#define COMPUTE0(BI)                                                         \
  {                                                                          \
    const char* base = (const char*)lds + (BI) * BUFB0;                      \
    _Pragma("unroll") for (int ks = 0; ks < 2; ++ks) {                       \
      bf16x8 af[4], bfr[2];                                                  \
      _Pragma("unroll") for (int f = 0; f < 4; ++f) {                        \
        int ra = wm * 64 + f * 16 + r16;                                     \
        af[f] = *(const bf16x8*)(base + ra * 128 +                           \
                                 ((ks * 64 + g4 * 16) ^ ((ra & 7) << 4)));   \
      }                                                                      \
      _Pragma("unroll") for (int f = 0; f < 2; ++f) {                        \
        int rb = wn * 32 + f * 16 + r16;                                     \
        bfr[f] = *(const bf16x8*)(base + 128 * 128 + rb * 128 +              \
                                  ((ks * 64 + g4 * 16) ^ ((rb & 7) << 4)));  \
      }                                                                      \
      _Pragma("unroll") for (int fm = 0; fm < 4; ++fm)                       \
        _Pragma("unroll") for (int fn = 0; fn < 2; ++fn)                     \
          acc[fm][fn] = mfma16(af[fm], bfr[fn], acc[fm][fn]);                \
    }                                                                        \
  }

#define STEP0(KT, RA, RB, RAN, RBN, LAST)                                    \
  __builtin_amdgcn_s_barrier();         /* WAR: compute(KT-1) done */        \
  WRITER0((KT) & 1, RA, RB);            /* compiler waits RA/RB loads */     \
  if (!(LAST)) { LOADR0((KT) + 1, RAN, RBN); }                               \
  __builtin_amdgcn_sched_barrier(0);                                         \
  asm volatile("s_waitcnt lgkmcnt(0)" ::: "memory");                         \
  __builtin_amdgcn_s_barrier();         /* RAW: all ds_writes visible */     \
  __builtin_amdgcn_sched_barrier(0);                                         \
  COMPUTE0((KT) & 1);

  f32x4 rA0[8], rB0[4], rA1[8], rB1[4];
  LOADR0(0, rA0, rB0);
  STEP0(0, rA0, rB0, rA1, rB1, 0)
  STEP0(1, rA1, rB1, rA0, rB0, 0)
  STEP0(2, rA0, rB0, rA1, rB1, 0)
  STEP0(3, rA1, rB1, rA0, rB0, 0)
  STEP0(4, rA0, rB0, rA1, rB1, 0)
  STEP0(5, rA1, rB1, rA0, rB0, 0)
  STEP0(6, rA0, rB0, rA1, rB1, 0)
  STEP0(7, rA1, rB1, rA0, rB0, 1)
#undef LOADR0
#undef WRITER0
#undef COMPUTE0
#undef STEP0

  #pragma unroll
  for (int fm = 0; fm < 4; ++fm) {
    #pragma unroll
    for (int fn = 0; fn < 2; ++fn) {
      int mb = mt * 128 + wm * 64 + fm * 16 + g4 * 4;
      int n = nt * 64 + wn * 32 + fn * 16 + r16;
      if (n < 512) {
        float bval = bq[n] * 0.125f;
        #pragma unroll
        for (int r = 0; r < 4; ++r)
          qb[(size_t)(mb + r) * DMODEL + n] = f2bf(acc[fm][fn][r] + bval);
      } else if (n < 1024) {
        int nn = n - 512;
        float bval = bk[nn];
        #pragma unroll
        for (int r = 0; r < 4; ++r)
          kb[(size_t)(mb + r) * DMODEL + nn] = f2bf(acc[fm][fn][r] + bval);
      } else {
        int nn = n - 1024;  // nn = h*64 + d ; vt[nn][m]
        float bval = bvv[nn];
        u16x4 pk;
        #pragma unroll
        for (int r = 0; r < 4; ++r) pk[r] = f2bf(acc[fm][fn][r] + bval);
        *(u16x4*)(vt + (size_t)nn * NTOK + mb) = pk;
      }
    }
  }

  // qrange table for attn (batch sorted); hidden under other blocks' work.
  if (mt == 0 && nt == 0) {
    int q0 = tid * 16;
    if (tid < 256) {
      int blo = batch[q0];
      int bhi = batch[q0 + 15];
      qrange[tid * 2]     = lbound(batch, blo) >> 6;
      qrange[tid * 2 + 1] = (lbound(batch, bhi + 1) + 63) >> 6;
    }
  }
}

// ======================= GEMM 1: fused convert + out-proj ==================
// out[4096x512] = aout(bf16)@Wo(fp32)^T + bo. BM=64,BN=64. A reg-staged bf16,
// B reg-staged fp32->bf16. Same pipeline/barrier structure as gemm_qkv.
#define BUFB1 (128 * 64 * 2)  // bytes per buffer (A 64x64 + B 64x64 bf16)

__global__ __launch_bounds__(256, 2) void gemm_out(
    const unsigned short* __restrict__ aout,
    const float* __restrict__ Wo, const float* __restrict__ bo,
    float* __restrict__ out) {
  __shared__ __align__(16) unsigned short lds[2 * 128 * 64];
  const int tid = threadIdx.x;
  const int lane = tid & 63;
  const int wv = tid >> 6;
  const int wm = wv >> 1, wn = wv & 1;
  const int r16 = lane & 15, g4 = lane >> 4;
  const int mt = blockIdx.x, nt = blockIdx.y;

  f32x4 acc[2][2];
  #pragma unroll
  for (int i = 0; i < 2; ++i)
    #pragma unroll
    for (int j = 0; j < 2; ++j)
      acc[i][j] = (f32x4){0.f, 0.f, 0.f, 0.f};

  const int srow = tid >> 3;
  const int c0 = (tid & 7) * 8;

#define LOADR1(KT, RA, RB)                                                   \
  {                                                                          \
    _Pragma("unroll") for (int i = 0; i < 2; ++i) {                          \
      int row = i * 32 + srow;                                               \
      int cs = c0 ^ ((row & 7) * 8);                                         \
      RA[i] = *(const u16x8*)(aout + (size_t)(mt * 64 + row) * KDIM +        \
                              (KT) * 64 + cs);                               \
    }                                                                        \
    _Pragma("unroll") for (int i = 0; i < 2; ++i) {                          \
      int row = i * 32 + srow;                                               \
      int cs = c0 ^ ((row & 7) * 8);                                         \
      const float* src = Wo + (size_t)(nt * 64 + row) * KDIM + (KT) * 64 + cs;\
      RB[2 * i]     = *(const f32x4*)src;                                    \
      RB[2 * i + 1] = *(const f32x4*)(src + 4);                              \
    }                                                                        \
  }

#define WRITER1(BI, RA, RB)                                                  \
  {                                                                          \
    char* bA = (char*)lds + (BI) * BUFB1;                                    \
    char* bB = bA + 64 * 128;                                                \
    _Pragma("unroll") for (int i = 0; i < 2; ++i)                            \
      *(u16x8*)(bA + i * 4096 + tid * 16) = RA[i];                           \
    _Pragma("unroll") for (int i = 0; i < 2; ++i) {                          \
      u16x8 pk;                                                              \
      _Pragma("unroll") for (int e = 0; e < 4; ++e) {                        \
        pk[e]     = f2bf(RB[2 * i][e]);                                      \
        pk[e + 4] = f2bf(RB[2 * i + 1][e]);                                  \
      }                                                                      \
      *(u16x8*)(bB + i * 4096 + tid * 16) = pk;                              \
    }                                                                        \
  }

#define COMPUTE1(BI)                                                         \
  {                                                                          \
    const char* base = (const char*)lds + (BI) * BUFB1;                      \
    _Pragma("unroll") for (int ks = 0; ks < 2; ++ks) {                       \
      bf16x8 af[2], bfr[2];                                                  \
      _Pragma("unroll") for (int f = 0; f < 2; ++f) {                        \
        int ra = wm * 32 + f * 16 + r16;                                     \
        af[f] = *(const bf16x8*)(base + ra * 128 +                           \
                                 ((ks * 64 + g4 * 16) ^ ((ra & 7) << 4)));   \
      }                                                                      \
      _Pragma("unroll") for (int f = 0; f < 2; ++f) {                        \
        int rb = wn * 32 + f * 16 + r16;                                     \
        bfr[f] = *(const bf16x8*)(base + 64 * 128 + rb * 128 +               \
                                  ((ks * 64 + g4 * 16) ^ ((rb & 7) << 4)));  \
      }                                                                      \
      _Pragma("unroll") for (int fm = 0; fm < 2; ++fm)                       \
        _Pragma("unroll") for (int fn = 0; fn < 2; ++fn)                     \
          acc[fm][fn] = mfma16(af[fm], bfr[fn], acc[fm][fn]);                \
    }                                                                        \
  }

#define STEP1(KT, RA, RB, RAN, RBN, LAST)                                    \
  __builtin_amdgcn_s_barrier();                                              \
  WRITER1((KT) & 1, RA, RB);                                                 \
  if (!(LAST)) { LOADR1((KT) + 1, RAN, RBN); }                               \
  __builtin_amdgcn_sched_barrier(0);                                         \
  asm volatile("s_waitcnt lgkmcnt(0)" ::: "memory");                         \
  __builtin_amdgcn_s_barrier();                                              \
  __builtin_amdgcn_sched_barrier(0);                                         \
  COMPUTE1((KT) & 1);

  u16x8 rA0[2], rA1[2];
  f32x4 rB0[4], rB1[4];
  LOADR1(0, rA0, rB0);
  STEP1(0, rA0, rB0, rA1, rB1, 0)
  STEP1(1, rA1, rB1, rA0, rB0, 0)
  STEP1(2, rA0, rB0, rA1, rB1, 0)
  STEP1(3, rA1, rB1, rA0, rB0, 0)
  STEP1(4, rA0, rB0, rA1, rB1, 0)
  STEP1(5, rA1, rB1, rA0, rB0, 0)
  STEP1(6, rA0, rB0, rA1, rB1, 0)
  STEP1(7, rA1, rB1, rA0, rB0, 1)
#undef LOADR1
#undef WRITER1
#undef COMPUTE1
#undef STEP1

  #pragma unroll
  for (int fm = 0; fm < 2; ++fm) {
    #pragma unroll
    for (int fn = 0; fn < 2; ++fn) {
      int mb = mt * 64 + wm * 32 + fm * 16 + g4 * 4;
      int n = nt * 64 + wn * 32 + fn * 16 + r16;
      float bval = bo[n];
      #pragma unroll
      for (int r = 0; r < 4; ++r)
        out[(size_t)(mb + r) * DMODEL + n] = acc[fm][fn][r] + bval;
    }
  }
}

// ---------------- flash attention (round-5 passing version, verbatim) -----
__global__ __launch_bounds__(64) void attn_kernel(
    const unsigned short* __restrict__ qb,
    const unsigned short* __restrict__ kb,
    const unsigned short* __restrict__ vt,
    const float* __restrict__ bias,
    const int* __restrict__ batch,
    const int* __restrict__ qrange,
    unsigned short* __restrict__ ao) {
  __shared__ __align__(16) unsigned short pl[16 * 72];
  const int lane = threadIdx.x & 63;
  const int r16 = lane & 15, g4 = lane >> 4;
  const int h = blockIdx.x & 7;
  const int qt = blockIdx.x >> 3;
  const int qrow0 = qt * 16;
  const int hoff = h * HDIM;

  const unsigned short* qrow = qb + (size_t)(qrow0 + r16) * DMODEL + hoff + g4 * 8;
  bf16x8 qa0 = *(const bf16x8*)qrow;
  bf16x8 qa1 = *(const bf16x8*)(qrow + 32);

  int qbt[4];
  const float* bprow[4];
  const float* bh = bias + (size_t)h * NTOK * NTOK;
  #pragma unroll
  for (int r = 0; r < 4; ++r) {
    qbt[r] = batch[qrow0 + g4 * 4 + r];
    bprow[r] = bh + (size_t)(qrow0 + g4 * 4 + r) * NTOK;
  }

  const int tile0 = qrange[qt * 2];
  const int tile1 = qrange[qt * 2 + 1];

  float m_r[4] = {NEGINF, NEGINF, NEGINF, NEGINF};
  float l_r[4] = {0.f, 0.f, 0.f, 0.f};
  f32x4 o[4];
  #pragma unroll
  for (int d = 0; d < 4; ++d) o[d] = (f32x4){0.f, 0.f, 0.f, 0.f};

#define PREFETCH_KB(T, K0, K1, BV, KBT)                                      \
  {                                                                          \
    int kvb_ = (T) << 6;                                                     \
    _Pragma("unroll") for (int c = 0; c < 4; ++c) {                          \
      const unsigned short* kp =                                             \
          kb + (size_t)(kvb_ + c * 16 + r16) * DMODEL + hoff + g4 * 8;       \
      K0[c] = *(const bf16x8*)kp;                                            \
      K1[c] = *(const bf16x8*)(kp + 32);                                     \
    }                                                                        \
    _Pragma("unroll") for (int c = 0; c < 4; ++c) {                          \
      KBT[c] = batch[kvb_ + c * 16 + r16];                                   \
      _Pragma("unroll") for (int r = 0; r < 4; ++r)                          \
        BV[c][r] = bprow[r][kvb_ + c * 16 + r16];                            \
    }                                                                        \
  }

#define TILE_STEP(T, K0C, K1C, BVC, KBTC, K0N, K1N, BVN, KBTN)               \
  {                                                                          \
    int kvb = (T) << 6;                                                      \
    f32x4 s[4];                                                              \
    __builtin_amdgcn_s_setprio(1);                                           \
    _Pragma("unroll") for (int c = 0; c < 4; ++c) {                          \
      f32x4 z = (f32x4){0.f, 0.f, 0.f, 0.f};                                 \
      z = mfma16(qa0, K0C[c], z);                                            \
      z = mfma16(qa1, K1C[c], z);                                            \
      s[c] = z;                                                              \
    }                                                                        \
    __builtin_amdgcn_s_setprio(0);                                           \
    bf16x8 v0[4], v1[4];                                                     \
    _Pragma("unroll") for (int d = 0; d < 4; ++d) {                          \
      const unsigned short* vp =                                             \
          vt + (size_t)(hoff + d * 16 + r16) * NTOK + kvb + g4 * 8;          \
      v0[d] = *(const bf16x8*)vp;                                            \
      v1[d] = *(const bf16x8*)(vp + 32);                                     \
    }                                                                        \
    {                                                                        \
      int tn_ = ((T) + 1 < tile1) ? (T) + 1 : (T);                           \
      PREFETCH_KB(tn_, K0N, K1N, BVN, KBTN);                                 \
    }                                                                        \
    _Pragma("unroll") for (int c = 0; c < 4; ++c)                            \
      _Pragma("unroll") for (int r = 0; r < 4; ++r)                          \
        s[c][r] = (qbt[r] == KBTC[c]) ? (s[c][r] + BVC[c][r]) : NEGINF;      \
    float scl[4];                                                            \
    _Pragma("unroll") for (int r = 0; r < 4; ++r) {                          \
      float tm = fmaxf(fmaxf(s[0][r], s[1][r]), fmaxf(s[2][r], s[3][r]));    \
      tm = fmaxf(tm, __shfl_xor(tm, 1));                                     \
      tm = fmaxf(tm, __shfl_xor(tm, 2));                                     \
      tm = fmaxf(tm, __shfl_xor(tm, 4));                                     \
      tm = fmaxf(tm, __shfl_xor(tm, 8));                                     \
      float mn = fmaxf(m_r[r], tm);                                          \
      bool dead = (mn == NEGINF);                                            \
      scl[r] = dead ? 1.0f : __expf(m_r[r] - mn);                            \
      m_r[r] = mn;                                                           \
      float rs = 0.f;                                                        \
      _Pragma("unroll") for (int c = 0; c < 4; ++c) {                        \
        float p = dead ? 0.0f : __expf(s[c][r] - mn);                        \
        s[c][r] = p;                                                         \
        rs += p;                                                             \
      }                                                                      \
      rs += __shfl_xor(rs, 1);                                               \
      rs += __shfl_xor(rs, 2);                                               \
      rs += __shfl_xor(rs, 4);                                               \
      rs += __shfl_xor(rs, 8);                                               \
      l_r[r] = l_r[r] * scl[r] + rs;                                         \
    }                                                                        \
    _Pragma("unroll") for (int c = 0; c < 4; ++c)                            \
      _Pragma("unroll") for (int r = 0; r < 4; ++r)                          \
        pl[(g4 * 4 + r) * 72 + c * 16 + r16] = f2bf(s[c][r]);                \
    asm volatile("" ::: "memory");                                           \
    u16x8 pr0 = *(const u16x8*)(pl + r16 * 72 + g4 * 8);                     \
    u16x8 pr1 = *(const u16x8*)(pl + r16 * 72 + 32 + g4 * 8);                \
    bf16x8 pa0 = __builtin_bit_cast(bf16x8, pr0);                            \
    bf16x8 pa1 = __builtin_bit_cast(bf16x8, pr1);                            \
    _Pragma("unroll") for (int d = 0; d < 4; ++d) {                          \
      _Pragma("unroll") for (int r = 0; r < 4; ++r) o[d][r] *= scl[r];       \
    }                                                                        \
    __builtin_amdgcn_s_setprio(1);                                           \
    _Pragma("unroll") for (int d = 0; d < 4; ++d) {                          \
      o[d] = mfma16(pa0, v0[d], o[d]);                                       \
      o[d] = mfma16(pa1, v1[d], o[d]);                                       \
    }                                                                        \
    __builtin_amdgcn_s_setprio(0);                                           \
  }

  bf16x8 ka0[4], ka1[4], kc0[4], kc1[4];
  float bva[4][4], bvb[4][4];
  int kta[4], ktb[4];
  PREFETCH_KB(tile0, ka0, ka1, bva, kta);
  int t = tile0;
  while (true) {
    TILE_STEP(t, ka0, ka1, bva, kta, kc0, kc1, bvb, ktb);
    if (++t >= tile1) break;
    TILE_STEP(t, kc0, kc1, bvb, ktb, ka0, ka1, bva, kta);
    if (++t >= tile1) break;
  }

  #pragma unroll
  for (int r = 0; r < 4; ++r) {
    float inv = (l_r[r] > 0.f) ? 1.0f / l_r[r] : 0.0f;
    #pragma unroll
    for (int d = 0; d < 4; ++d)
      ao[(size_t)(qrow0 + g4 * 4 + r) * DMODEL + hoff + d * 16 + r16] =
          f2bf(o[d][r] * inv);
  }
#undef PREFETCH_KB
#undef TILE_STEP
}

// ---------------------------------------------------------------------------
extern "C" void kernel_launch(void* const* d_in, const int* in_sizes, int n_in,
                              void* d_out, int out_size, void* d_ws, size_t ws_size,
                              hipStream_t stream) {
  const float* x  = (const float*)d_in[0];
  const float* ab = (const float*)d_in[1];
  const int* batch = (const int*)d_in[2];
  const float* Wq = (const float*)d_in[3];
  const float* bq = (const float*)d_in[4];
  const float* Wk = (const float*)d_in[5];
  const float* bk = (const float*)d_in[6];
  const float* Wv = (const float*)d_in[7];
  const float* bv = (const float*)d_in[8];
  const float* Wo = (const float*)d_in[9];
  const float* bo = (const float*)d_in[10];
  float* out = (float*)d_out;

  char* ws = (char*)d_ws;
  const size_t MB = 1024 * 1024;
  unsigned short* qb   = (unsigned short*)(ws);            // 4 MB
  unsigned short* kb   = (unsigned short*)(ws + 4 * MB);   // 4 MB
  unsigned short* vt   = (unsigned short*)(ws + 8 * MB);   // 4 MB  [h*64+d][n]
  unsigned short* aout = (unsigned short*)(ws + 12 * MB);  // 4 MB
  int* qrange          = (int*)(ws + 16 * MB);             // 2 KB

  gemm_qkv<<<dim3(32, 24), dim3(256), 0, stream>>>(
      x, Wq, bq, Wk, bk, Wv, bv, batch, qb, kb, vt, qrange);

  attn_kernel<<<dim3(2048), dim3(64), 0, stream>>>(
      qb, kb, vt, ab, batch, qrange, aout);

  gemm_out<<<dim3(64, 8), dim3(256), 0, stream>>>(aout, Wo, bo, out);
}